// Round 2
// baseline (1091.657 us; speedup 1.0000x reference)
//
#include <hip/hip_runtime.h>

typedef __bf16 bf16_t;
typedef __bf16 bf16x4 __attribute__((ext_vector_type(4)));
typedef __bf16 bf16x8 __attribute__((ext_vector_type(8)));
typedef float f32x4 __attribute__((ext_vector_type(4)));

#define LDA 40   // padded LDS K-stride (32 + 8): 20 words/row -> 2-way max aliasing

// ---------------------------------------------------------------------------
// GEMM: C[M][N] = A[M][K] * B[N][K]^T   (B row-major N x K)
// fp32 global inputs converted to bf16 in LDS; fp32 MFMA accumulate.
// Block: 256 threads (4 waves). Tile: 128(M) x 64(N), BK = 32.
// Wave w owns M-rows [w*32, w*32+32): 2(M) x 4(N) mfma_f32_16x16x32_bf16.
// MODE 0: A fp32 (x), scatter epilogue -> bf16 q/k/v in (B,H,T,hd) layout
// MODE 1: A bf16 (y in ws), plain fp32 store -> of[m*2048 + n]
// ---------------------------------------------------------------------------
template <int MODE>
__global__ __launch_bounds__(256)
void gemm_bt(const void* __restrict__ Av, const float* __restrict__ Bm, int K,
             bf16_t* __restrict__ o0, bf16_t* __restrict__ o1, bf16_t* __restrict__ o2,
             float* __restrict__ of)
{
    __shared__ __align__(16) bf16_t As[128 * LDA];
    __shared__ __align__(16) bf16_t Bs[64 * LDA];
    const int tid  = threadIdx.x;
    const int lane = tid & 63;
    const int w    = tid >> 6;
    const int m0   = blockIdx.x * 128;
    const int n0   = blockIdx.y * 64;

    f32x4 acc[2][4];
#pragma unroll
    for (int i = 0; i < 2; ++i)
#pragma unroll
        for (int j = 0; j < 4; ++j)
            acc[i][j] = (f32x4){0.f, 0.f, 0.f, 0.f};

    // fp32 staging map: 256 thr x float4 = 1024 elems/pass
    const int fr = tid >> 3;          // 0..31
    const int fc = (tid & 3 + 0, (tid & 7) * 4); // (comma op avoided below; kept simple)
    const int fc4 = (tid & 7) * 4;    // 0,4,...,28
    // bf16 staging map (MODE 1 A): 256 thr x 8 elems = 2048 elems/pass
    const int ar = tid >> 2;          // 0..63
    const int ac = (tid & 3) * 8;     // 0,8,16,24
    (void)fc;

    for (int k0 = 0; k0 < K; k0 += 32) {
        __syncthreads();
        if (MODE == 0) {
            const float* A = (const float*)Av;
#pragma unroll
            for (int p = 0; p < 4; ++p) {
                const int row = p * 32 + fr;
                f32x4 f = *(const f32x4*)&A[(size_t)(m0 + row) * K + k0 + fc4];
                bf16x4 h = {(bf16_t)f[0], (bf16_t)f[1], (bf16_t)f[2], (bf16_t)f[3]};
                *(bf16x4*)&As[row * LDA + fc4] = h;
            }
        } else {
            const bf16_t* A = (const bf16_t*)Av;
            *(uint4*)&As[ar * LDA + ac]        = *(const uint4*)&A[(size_t)(m0 + ar) * K + k0 + ac];
            *(uint4*)&As[(ar + 64) * LDA + ac] = *(const uint4*)&A[(size_t)(m0 + ar + 64) * K + k0 + ac];
        }
#pragma unroll
        for (int p = 0; p < 2; ++p) {
            const int row = p * 32 + fr;
            f32x4 f = *(const f32x4*)&Bm[(size_t)(n0 + row) * K + k0 + fc4];
            bf16x4 h = {(bf16_t)f[0], (bf16_t)f[1], (bf16_t)f[2], (bf16_t)f[3]};
            *(bf16x4*)&Bs[row * LDA + fc4] = h;
        }
        __syncthreads();

        const int kq = (lane >> 4) * 8;   // k-offset for this lane quad
        bf16x8 a0 = *(const bf16x8*)&As[(w * 32      + (lane & 15)) * LDA + kq];
        bf16x8 a1 = *(const bf16x8*)&As[(w * 32 + 16 + (lane & 15)) * LDA + kq];
#pragma unroll
        for (int n = 0; n < 4; ++n) {
            bf16x8 b = *(const bf16x8*)&Bs[(n * 16 + (lane & 15)) * LDA + kq];
            acc[0][n] = __builtin_amdgcn_mfma_f32_16x16x32_bf16(a0, b, acc[0][n], 0, 0, 0);
            acc[1][n] = __builtin_amdgcn_mfma_f32_16x16x32_bf16(a1, b, acc[1][n], 0, 0, 0);
        }
    }

    // epilogue: C/D layout col = lane&15, row = (lane>>4)*4 + r  [m89/m91-verified]
#pragma unroll
    for (int ms = 0; ms < 2; ++ms) {
#pragma unroll
        for (int n = 0; n < 4; ++n) {
#pragma unroll
            for (int r = 0; r < 4; ++r) {
                const int m = m0 + w * 32 + ms * 16 + (lane >> 4) * 4 + r;
                const int f = n0 + n * 16 + (lane & 15);
                const float val = acc[ms][n][r];
                if (MODE == 0) {
                    // f -> (which, h, d); store bf16 to (B,H,T,hd)
                    const int b     = m >> 9;          // T = 512
                    const int t     = m & 511;
                    const int which = f >> 11;         // / 2048
                    const int h     = (f >> 7) & 15;
                    const int d     = f & 127;
                    bf16_t* dst = (which == 0) ? o0 : (which == 1) ? o1 : o2;
                    dst[(size_t)(((b << 4) + h) * 512 + t) * 128 + d] = (bf16_t)val;
                } else {
                    of[(size_t)m * 2048 + f] = val;
                }
            }
        }
    }
}

// ---------------------------------------------------------------------------
// RoPE (in-place on bf16 q and k): per (arr, bh, t, d<8) rotate (d, d+8).
// freq_d = 10000^(-d/8);  out[d] = x1*cos - x2*sin; out[d+8] = x2*cos + x1*sin
// ---------------------------------------------------------------------------
__global__ void rope_kernel(bf16_t* __restrict__ q, bf16_t* __restrict__ k)
{
    const int id  = blockIdx.x * 256 + threadIdx.x;   // 0 .. 2^20-1
    const int arr = id >> 19;
    const int rem = id & ((1 << 19) - 1);
    const int bh  = rem >> 12;          // 0..127
    const int t   = (rem >> 3) & 511;
    const int d   = rem & 7;

    bf16_t* p = (arr ? k : q) + (size_t)(bh * 512 + t) * 128;
    const float x1 = (float)p[d];
    const float x2 = (float)p[d + 8];
    const float freq = __expf(-(float)d * 1.1512925464970229f);  // ln(10000)/8
    const float ang  = (float)t * freq;
    const float c = cosf(ang), s = sinf(ang);
    p[d]     = (bf16_t)(x1 * c - x2 * s);
    p[d + 8] = (bf16_t)(x2 * c + x1 * s);
}

// ---------------------------------------------------------------------------
// Flash attention (scalar, fp32 online softmax). One block per (b, h, 32-row
// q-tile); 256 threads. 32-wide K/V tiles staged in LDS. Causal.
// Writes y (bf16) in (B, T, H*hd) layout.
// ---------------------------------------------------------------------------
#define QLD 136   // 128 + 8 pad
#define SLD 33
#define OLD 129

__global__ __launch_bounds__(256)
void flash_attn(const bf16_t* __restrict__ q, const bf16_t* __restrict__ k,
                const bf16_t* __restrict__ v, bf16_t* __restrict__ y)
{
    const int qt = blockIdx.x;   // 0..15
    const int h  = blockIdx.y;   // 0..15
    const int b  = blockIdx.z;   // 0..7
    const int tid = threadIdx.x;

    __shared__ __align__(16) bf16_t Qs[32 * QLD];
    __shared__ __align__(16) bf16_t Ks[32 * QLD];
    __shared__ __align__(16) bf16_t Vs[32 * QLD];
    __shared__ float S[32 * SLD];
    __shared__ float Os[32 * OLD];
    __shared__ float mS[32], lS[32], aS[32];

    const bf16_t* qb = q + (size_t)((b * 16 + h) * 512) * 128;
    const bf16_t* kb = k + (size_t)((b * 16 + h) * 512) * 128;
    const bf16_t* vb = v + (size_t)((b * 16 + h) * 512) * 128;

#pragma unroll
    for (int it = 0; it < 2; ++it) {
        const int vec = it * 256 + tid;
        const int r = vec >> 4, c = (vec & 15) * 8;
        *(uint4*)&Qs[r * QLD + c] = *(const uint4*)&qb[(size_t)(qt * 32 + r) * 128 + c];
    }
    for (int e = tid; e < 32 * OLD; e += 256) Os[e] = 0.f;
    if (tid < 32) { mS[tid] = -INFINITY; lS[tid] = 0.f; }
    __syncthreads();

    const float scale = 0.08838834764831845f;   // 1/sqrt(128)
    const int i  = tid >> 3;          // query row 0..31
    const int j0 = (tid & 7) * 4;     // 4 consecutive keys
    const int d0 = (tid & 7) * 16;    // 16 consecutive dims

    for (int kt = 0; kt <= qt; ++kt) {
#pragma unroll
        for (int it = 0; it < 2; ++it) {
            const int vec = it * 256 + tid;
            const int r = vec >> 4, c = (vec & 15) * 8;
            *(uint4*)&Ks[r * QLD + c] = *(const uint4*)&kb[(size_t)(kt * 32 + r) * 128 + c];
            *(uint4*)&Vs[r * QLD + c] = *(const uint4*)&vb[(size_t)(kt * 32 + r) * 128 + c];
        }
        __syncthreads();

        float sv0 = 0.f, sv1 = 0.f, sv2 = 0.f, sv3 = 0.f;
        for (int d = 0; d < 128; ++d) {
            const float qd = (float)Qs[i * QLD + d];
            sv0 += qd * (float)Ks[(j0 + 0) * QLD + d];
            sv1 += qd * (float)Ks[(j0 + 1) * QLD + d];
            sv2 += qd * (float)Ks[(j0 + 2) * QLD + d];
            sv3 += qd * (float)Ks[(j0 + 3) * QLD + d];
        }
        {
            const int ig = qt * 32 + i;
            const float svs[4] = {sv0, sv1, sv2, sv3};
#pragma unroll
            for (int jj = 0; jj < 4; ++jj) {
                const int jg = kt * 32 + j0 + jj;
                S[i * SLD + j0 + jj] = (jg <= ig) ? svs[jj] * scale : -INFINITY;
            }
        }
        __syncthreads();

        if (tid < 32) {
            const int r = tid;
            float mt = -INFINITY;
            for (int j = 0; j < 32; ++j) mt = fmaxf(mt, S[r * SLD + j]);
            const float mn = fmaxf(mS[r], mt);
            const float alpha = __expf(mS[r] - mn);   // first tile: exp(-inf)=0
            float sum = 0.f;
            for (int j = 0; j < 32; ++j) {
                const float p = __expf(S[r * SLD + j] - mn);
                S[r * SLD + j] = p;
                sum += p;
            }
            lS[r] = lS[r] * alpha + sum;
            mS[r] = mn;
            aS[r] = alpha;
        }
        __syncthreads();

        {
            float o[16];
            const float a = aS[i];
#pragma unroll
            for (int dd = 0; dd < 16; ++dd) o[dd] = Os[i * OLD + d0 + dd] * a;
            for (int j = 0; j < 32; ++j) {
                const float p = S[i * SLD + j];
#pragma unroll
                for (int dd = 0; dd < 16; ++dd)
                    o[dd] += p * (float)Vs[j * QLD + d0 + dd];
            }
#pragma unroll
            for (int dd = 0; dd < 16; ++dd) Os[i * OLD + d0 + dd] = o[dd];
        }
        __syncthreads();
    }

    for (int e = tid; e < 32 * 128; e += 256) {
        const int r = e >> 7, d = e & 127;
        const float val = Os[r * OLD + d] / lS[r];
        y[(size_t)(b * 512 + qt * 32 + r) * 2048 + h * 128 + d] = (bf16_t)val;
    }
}

// ---------------------------------------------------------------------------
extern "C" void kernel_launch(void* const* d_in, const int* in_sizes, int n_in,
                              void* d_out, int out_size, void* d_ws, size_t ws_size,
                              hipStream_t stream)
{
    (void)in_sizes; (void)n_in; (void)out_size; (void)ws_size;

    const float* x    = (const float*)d_in[0];   // (8, 512, 2048) fp32
    const float* Wqkv = (const float*)d_in[1];   // (6144, 2048)  fp32
    const float* Wout = (const float*)d_in[2];   // (2048, 2048)  fp32
    float* out = (float*)d_out;                  // (8, 512, 2048) fp32

    const size_t SEG = (size_t)8 * 16 * 512 * 128; // 8,388,608 elems (bf16 -> 16 MB)
    bf16_t* q = (bf16_t*)d_ws;
    bf16_t* k = q + SEG;
    bf16_t* v = k + SEG;
    bf16_t* y = v + SEG;                           // (4096, 2048) bf16 — 64 MB total

    // 1) qkv = x @ Wqkv^T  (fp32 in, bf16 out, scattered to (B,H,T,hd))
    gemm_bt<0><<<dim3(4096 / 128, 6144 / 64), 256, 0, stream>>>(x, Wqkv, 2048, q, k, v, nullptr);
    // 2) RoPE in-place on q, k (first 16 dims)
    rope_kernel<<<(2 * 128 * 512 * 8) / 256, 256, 0, stream>>>(q, k);
    // 3) causal flash attention -> y (B, T, C) bf16
    flash_attn<<<dim3(16, 16, 8), 256, 0, stream>>>(q, k, v, y);
    // 4) out = y @ Wout^T  (bf16 A, fp32 B-convert, fp32 store)
    gemm_bt<1><<<dim3(4096 / 128, 2048 / 64), 256, 0, stream>>>(y, Wout, 2048, nullptr, nullptr, nullptr, out);
}

// Round 3
// 477.189 us; speedup vs baseline: 2.2877x; 2.2877x over previous
//
#include <hip/hip_runtime.h>

typedef __bf16 bf16_t;
typedef __bf16 bf16x4 __attribute__((ext_vector_type(4)));
typedef __bf16 bf16x8 __attribute__((ext_vector_type(8)));
typedef float f32x4 __attribute__((ext_vector_type(4)));

#define LDA 40   // GEMM LDS K-stride (32 + 8): 2-way max bank aliasing

// ---------------------------------------------------------------------------
// GEMM: C[M][N] = A[M][K] * B[N][K]^T   (B row-major N x K)
// fp32 global inputs converted to bf16 in LDS; fp32 MFMA accumulate.
// Block: 256 threads (4 waves). Tile: 128(M) x 64(N), BK = 32.
// MODE 0: A fp32 (x); scatter epilogue -> bf16 q/k (B,H,T,hd) and v (B,H,hd,T)
// MODE 1: A bf16 (y in ws); plain fp32 store -> of[m*2048 + n]
// ---------------------------------------------------------------------------
template <int MODE>
__global__ __launch_bounds__(256)
void gemm_bt(const void* __restrict__ Av, const float* __restrict__ Bm, int K,
             bf16_t* __restrict__ o0, bf16_t* __restrict__ o1, bf16_t* __restrict__ o2,
             float* __restrict__ of)
{
    __shared__ __align__(16) bf16_t As[128 * LDA];
    __shared__ __align__(16) bf16_t Bs[64 * LDA];
    const int tid  = threadIdx.x;
    const int lane = tid & 63;
    const int w    = tid >> 6;
    const int m0   = blockIdx.x * 128;
    const int n0   = blockIdx.y * 64;

    f32x4 acc[2][4];
#pragma unroll
    for (int i = 0; i < 2; ++i)
#pragma unroll
        for (int j = 0; j < 4; ++j)
            acc[i][j] = (f32x4){0.f, 0.f, 0.f, 0.f};

    const int fr  = tid >> 3;         // 0..31
    const int fc4 = (tid & 7) * 4;    // 0,4,...,28
    const int ar  = tid >> 2;         // 0..63
    const int ac  = (tid & 3) * 8;    // 0,8,16,24

    for (int k0 = 0; k0 < K; k0 += 32) {
        __syncthreads();
        if (MODE == 0) {
            const float* A = (const float*)Av;
#pragma unroll
            for (int p = 0; p < 4; ++p) {
                const int row = p * 32 + fr;
                f32x4 f = *(const f32x4*)&A[(size_t)(m0 + row) * K + k0 + fc4];
                bf16x4 h = {(bf16_t)f[0], (bf16_t)f[1], (bf16_t)f[2], (bf16_t)f[3]};
                *(bf16x4*)&As[row * LDA + fc4] = h;
            }
        } else {
            const bf16_t* A = (const bf16_t*)Av;
            *(uint4*)&As[ar * LDA + ac]        = *(const uint4*)&A[(size_t)(m0 + ar) * K + k0 + ac];
            *(uint4*)&As[(ar + 64) * LDA + ac] = *(const uint4*)&A[(size_t)(m0 + ar + 64) * K + k0 + ac];
        }
#pragma unroll
        for (int p = 0; p < 2; ++p) {
            const int row = p * 32 + fr;
            f32x4 f = *(const f32x4*)&Bm[(size_t)(n0 + row) * K + k0 + fc4];
            bf16x4 h = {(bf16_t)f[0], (bf16_t)f[1], (bf16_t)f[2], (bf16_t)f[3]};
            *(bf16x4*)&Bs[row * LDA + fc4] = h;
        }
        __syncthreads();

        const int kq = ((lane >> 4)) * 8;
        bf16x8 a0 = *(const bf16x8*)&As[(w * 32      + (lane & 15)) * LDA + kq];
        bf16x8 a1 = *(const bf16x8*)&As[(w * 32 + 16 + (lane & 15)) * LDA + kq];
#pragma unroll
        for (int n = 0; n < 4; ++n) {
            bf16x8 b = *(const bf16x8*)&Bs[(n * 16 + (lane & 15)) * LDA + kq];
            acc[0][n] = __builtin_amdgcn_mfma_f32_16x16x32_bf16(a0, b, acc[0][n], 0, 0, 0);
            acc[1][n] = __builtin_amdgcn_mfma_f32_16x16x32_bf16(a1, b, acc[1][n], 0, 0, 0);
        }
    }

    // epilogue: C/D layout col = lane&15, row = (lane>>4)*4 + r
#pragma unroll
    for (int ms = 0; ms < 2; ++ms) {
#pragma unroll
        for (int n = 0; n < 4; ++n) {
#pragma unroll
            for (int r = 0; r < 4; ++r) {
                const int m = m0 + w * 32 + ms * 16 + (lane >> 4) * 4 + r;
                const int f = n0 + n * 16 + (lane & 15);
                const float val = acc[ms][n][r];
                if (MODE == 0) {
                    const int b     = m >> 9;          // T = 512
                    const int t     = m & 511;
                    const int which = f >> 11;
                    const int h     = (f >> 7) & 15;
                    const int d     = f & 127;
                    if (which == 2) {
                        // v stored transposed: (B, H, hd, T) — flash stages V^T directly
                        o2[((size_t)(((b << 4) + h) * 128 + d) << 9) + t] = (bf16_t)val;
                    } else {
                        bf16_t* dst = (which == 0) ? o0 : o1;
                        dst[(size_t)(((b << 4) + h) * 512 + t) * 128 + d] = (bf16_t)val;
                    }
                } else {
                    of[(size_t)m * 2048 + f] = val;
                }
            }
        }
    }
}

// ---------------------------------------------------------------------------
// RoPE (in-place on bf16 q and k; v untouched)
// ---------------------------------------------------------------------------
__global__ void rope_kernel(bf16_t* __restrict__ q, bf16_t* __restrict__ k)
{
    const int id  = blockIdx.x * 256 + threadIdx.x;
    const int arr = id >> 19;
    const int rem = id & ((1 << 19) - 1);
    const int bh  = rem >> 12;
    const int t   = (rem >> 3) & 511;
    const int d   = rem & 7;

    bf16_t* p = (arr ? k : q) + (size_t)(bh * 512 + t) * 128;
    const float x1 = (float)p[d];
    const float x2 = (float)p[d + 8];
    const float freq = __expf(-(float)d * 1.1512925464970229f);  // ln(10000)/8
    const float ang  = (float)t * freq;
    const float c = cosf(ang), s = sinf(ang);
    p[d]     = (bf16_t)(x1 * c - x2 * s);
    p[d + 8] = (bf16_t)(x2 * c + x1 * s);
}

// ---------------------------------------------------------------------------
// MFMA flash attention. Block = 256 thr (4 waves) per (b, h, 64-query tile).
// Wave w owns queries w*16..w*16+15. K-tile = 64 keys.
//  S^T = K·Q^T  (A = K from LDS, B = Q frags in registers; query = lane&15)
//  softmax: 16 in-lane scores + shfl_xor(16,32) cross-quad reduce
//  P -> LDS (bf16), O += P·V via MFMA (V^T staged from (B,H,hd,T) global)
// LDS strides: 16B-aligned rows, >=8 distinct bank starts for b128 ops.
// ---------------------------------------------------------------------------
#define KLD 136
#define VLD 72
#define PLD 72

__global__ __launch_bounds__(256)
void flash_attn(const bf16_t* __restrict__ q, const bf16_t* __restrict__ k,
                const bf16_t* __restrict__ vT, bf16_t* __restrict__ y)
{
    const int qt = blockIdx.x;   // 0..7 (64-query tiles)
    const int h  = blockIdx.y;
    const int b  = blockIdx.z;
    const int tid  = threadIdx.x;
    const int lane = tid & 63;
    const int w    = tid >> 6;
    const int quad = lane >> 4;
    const int qcol = lane & 15;

    __shared__ __align__(16) bf16_t Ks[64 * KLD];      // keys x dims
    __shared__ __align__(16) bf16_t VTs[128 * VLD];    // dims x keys
    __shared__ __align__(16) bf16_t Ps[64 * PLD];      // queries x keys
    __shared__ __align__(16) float aS[4][16];
    __shared__ __align__(16) float lS[4][16];

    const bf16_t* qb  = q  + (size_t)((b * 16 + h) * 512) * 128;
    const bf16_t* kb  = k  + (size_t)((b * 16 + h) * 512) * 128;
    const bf16_t* vtb = vT + (size_t)((b * 16 + h) * 128) * 512;

    // Q fragments (B-operand): n = lane&15 -> query, k = kc*32 + quad*8 + j
    bf16x8 qfrag[4];
    const int qrow = qt * 64 + w * 16 + qcol;
#pragma unroll
    for (int kc = 0; kc < 4; ++kc)
        qfrag[kc] = *(const bf16x8*)&qb[(size_t)qrow * 128 + kc * 32 + quad * 8];

    f32x4 acc_o[8];
#pragma unroll
    for (int nt = 0; nt < 8; ++nt) acc_o[nt] = (f32x4){0.f, 0.f, 0.f, 0.f};
    float m_run = -INFINITY, l_run = 0.f;
    const float scale = 0.08838834764831845f;   // 1/sqrt(128)

    for (int kt = 0; kt <= qt; ++kt) {
        __syncthreads();
        // stage K tile (64 x 128)
#pragma unroll
        for (int p = 0; p < 4; ++p) {
            const int r = p * 16 + (tid >> 4), c = (tid & 15) * 8;
            *(uint4*)&Ks[r * KLD + c] = *(const uint4*)&kb[(size_t)(kt * 64 + r) * 128 + c];
        }
        // stage V^T tile (128 dims x 64 keys) — v already transposed in global
#pragma unroll
        for (int p = 0; p < 4; ++p) {
            const int r = p * 32 + (tid >> 3), c = (tid & 7) * 8;
            *(uint4*)&VTs[r * VLD + c] = *(const uint4*)&vtb[(size_t)r * 512 + kt * 64 + c];
        }
        __syncthreads();

        // S^T (M=64 keys, N=16 queries, K=128 dims): 16 MFMA
        f32x4 sacc[4];
#pragma unroll
        for (int mt = 0; mt < 4; ++mt) sacc[mt] = (f32x4){0.f, 0.f, 0.f, 0.f};
#pragma unroll
        for (int mt = 0; mt < 4; ++mt)
#pragma unroll
            for (int kc = 0; kc < 4; ++kc) {
                bf16x8 af = *(const bf16x8*)&Ks[(mt * 16 + qcol) * KLD + kc * 32 + quad * 8];
                sacc[mt] = __builtin_amdgcn_mfma_f32_16x16x32_bf16(af, qfrag[kc], sacc[mt], 0, 0, 0);
            }

        // lane holds S^T[key = mt*16 + quad*4 + r][query = w*16 + qcol]
        float s[16];
#pragma unroll
        for (int mt = 0; mt < 4; ++mt)
#pragma unroll
            for (int r = 0; r < 4; ++r)
                s[mt * 4 + r] = sacc[mt][r] * scale;
        if (kt == qt) {   // only diagonal tiles need the causal mask
#pragma unroll
            for (int mt = 0; mt < 4; ++mt)
#pragma unroll
                for (int r = 0; r < 4; ++r)
                    if (mt * 16 + quad * 4 + r > w * 16 + qcol)
                        s[mt * 4 + r] = -1e30f;
        }

        // online softmax: in-lane over 16, cross-quad via shfl_xor
        float mx = s[0];
#pragma unroll
        for (int i = 1; i < 16; ++i) mx = fmaxf(mx, s[i]);
        mx = fmaxf(mx, __shfl_xor(mx, 16));
        mx = fmaxf(mx, __shfl_xor(mx, 32));
        const float m_new = fmaxf(m_run, mx);
        const float alpha = __expf(m_run - m_new);   // first iter: exp(-inf)=0
        float p16[16];
        float sum = 0.f;
#pragma unroll
        for (int i = 0; i < 16; ++i) { p16[i] = __expf(s[i] - m_new); sum += p16[i]; }
        sum += __shfl_xor(sum, 16);
        sum += __shfl_xor(sum, 32);
        l_run = l_run * alpha + sum;
        m_run = m_new;
        if (quad == 0) aS[w][qcol] = alpha;

        // P -> LDS (rows = query, cols = key); wave-private region, no barrier
#pragma unroll
        for (int mt = 0; mt < 4; ++mt) {
            bf16x4 pb = {(bf16_t)p16[mt * 4 + 0], (bf16_t)p16[mt * 4 + 1],
                         (bf16_t)p16[mt * 4 + 2], (bf16_t)p16[mt * 4 + 3]};
            *(bf16x4*)&Ps[(w * 16 + qcol) * PLD + mt * 16 + quad * 4] = pb;
        }

        // rescale O rows (query = quad*4 + r) by alpha
        f32x4 alpha4 = *(const f32x4*)&aS[w][quad * 4];
#pragma unroll
        for (int nt = 0; nt < 8; ++nt)
#pragma unroll
            for (int r = 0; r < 4; ++r)
                acc_o[nt][r] *= alpha4[r];

        // O += P·V (M=16 queries, N=128 dims, K=64 keys): 16 MFMA
#pragma unroll
        for (int kc2 = 0; kc2 < 2; ++kc2) {
            bf16x8 pf = *(const bf16x8*)&Ps[(w * 16 + qcol) * PLD + kc2 * 32 + quad * 8];
#pragma unroll
            for (int nt = 0; nt < 8; ++nt) {
                bf16x8 vf = *(const bf16x8*)&VTs[(nt * 16 + qcol) * VLD + kc2 * 32 + quad * 8];
                acc_o[nt] = __builtin_amdgcn_mfma_f32_16x16x32_bf16(pf, vf, acc_o[nt], 0, 0, 0);
            }
        }
    }

    // epilogue: y[(b, t, h*128 + d)] = O / l
    if (quad == 0) lS[w][qcol] = l_run;
    f32x4 l4 = *(const f32x4*)&lS[w][quad * 4];
#pragma unroll
    for (int nt = 0; nt < 8; ++nt)
#pragma unroll
        for (int r = 0; r < 4; ++r) {
            const int t  = qt * 64 + w * 16 + quad * 4 + r;
            const int cc = h * 128 + nt * 16 + qcol;
            y[(size_t)(b * 512 + t) * 2048 + cc] = (bf16_t)(acc_o[nt][r] / l4[r]);
        }
}

// ---------------------------------------------------------------------------
extern "C" void kernel_launch(void* const* d_in, const int* in_sizes, int n_in,
                              void* d_out, int out_size, void* d_ws, size_t ws_size,
                              hipStream_t stream)
{
    (void)in_sizes; (void)n_in; (void)out_size; (void)ws_size;

    const float* x    = (const float*)d_in[0];   // (8, 512, 2048) fp32
    const float* Wqkv = (const float*)d_in[1];   // (6144, 2048)  fp32
    const float* Wout = (const float*)d_in[2];   // (2048, 2048)  fp32
    float* out = (float*)d_out;                  // (8, 512, 2048) fp32

    const size_t SEG = (size_t)8 * 16 * 512 * 128;
    bf16_t* q  = (bf16_t*)d_ws;                  // (B,H,T,hd)
    bf16_t* k  = q + SEG;                        // (B,H,T,hd)
    bf16_t* vT = k + SEG;                        // (B,H,hd,T)  <- transposed
    bf16_t* y  = vT + SEG;                       // (B,T,C)

    gemm_bt<0><<<dim3(4096 / 128, 6144 / 64), 256, 0, stream>>>(x, Wqkv, 2048, q, k, vT, nullptr);
    rope_kernel<<<(2 * 128 * 512 * 8) / 256, 256, 0, stream>>>(q, k);
    flash_attn<<<dim3(8, 16, 8), 256, 0, stream>>>(q, k, vT, y);
    gemm_bt<1><<<dim3(4096 / 128, 2048 / 64), 256, 0, stream>>>(y, Wout, 2048, nullptr, nullptr, nullptr, out);
}

// Round 4
// 391.302 us; speedup vs baseline: 2.7898x; 1.2195x over previous
//
#include <hip/hip_runtime.h>

typedef __bf16 bf16_t;
typedef __bf16 bf16x4 __attribute__((ext_vector_type(4)));
typedef __bf16 bf16x8 __attribute__((ext_vector_type(8)));
typedef float f32x4 __attribute__((ext_vector_type(4)));

#define GLB(p) ((const __attribute__((address_space(1))) void*)(p))
#define LDS(p) ((__attribute__((address_space(3))) void*)(p))

// ---------------------------------------------------------------------------
// fp32 -> bf16 bulk convert (8 elems/thread, 16B stores)
// ---------------------------------------------------------------------------
__global__ void f32_to_bf16(const float* __restrict__ src, bf16_t* __restrict__ dst, int n8)
{
    const int i = blockIdx.x * 256 + threadIdx.x;
    if (i >= n8) return;
    const f32x4 a = *(const f32x4*)&src[(size_t)i * 8];
    const f32x4 b = *(const f32x4*)&src[(size_t)i * 8 + 4];
    bf16x8 h = {(bf16_t)a[0], (bf16_t)a[1], (bf16_t)a[2], (bf16_t)a[3],
                (bf16_t)b[0], (bf16_t)b[1], (bf16_t)b[2], (bf16_t)b[3]};
    *(bf16x8*)&dst[(size_t)i * 8] = h;
}

// ---------------------------------------------------------------------------
// m97-structure GEMM: C[M][N] = A[M][K] * B[N][K]^T, all-bf16 global inputs.
// 128x128 tile, BK=32, 256 thr (4 waves, 2x2), wave = 64x64 = 4x4 MFMA tiles.
// Staging: global_load_lds width=16 into UNPADDED LDS (lane-contiguous dest),
// XOR swizzle cg = (l&3)^(row&3) applied on the global-address side so the
// fragment ds_read_b128 is 4-way (1.58x) instead of 8-way (2.94x) aliased.
// MODE 0: scatter epilogue -> bf16 q/k (B,H,T,hd) and vT (B,H,hd,T)
// MODE 1: fp32 store -> of[m*2048 + n]
// ---------------------------------------------------------------------------
template <int MODE>
__global__ __launch_bounds__(256)
void gemm_bt(const bf16_t* __restrict__ A, const bf16_t* __restrict__ Bm, int K,
             bf16_t* __restrict__ o0, bf16_t* __restrict__ o1, bf16_t* __restrict__ o2,
             float* __restrict__ of)
{
    __shared__ __align__(16) bf16_t As[128 * 32];
    __shared__ __align__(16) bf16_t Bs[128 * 32];
    const int tid  = threadIdx.x;
    const int lane = tid & 63;
    const int w    = tid >> 6;
    const int wm   = (w & 1) * 64;
    const int wn   = (w >> 1) * 64;
    const int m0   = blockIdx.x * 128;
    const int n0   = blockIdx.y * 128;
    const int quad = lane >> 4;
    const int qcol = lane & 15;

    f32x4 acc[4][4];
#pragma unroll
    for (int i = 0; i < 4; ++i)
#pragma unroll
        for (int j = 0; j < 4; ++j)
            acc[i][j] = (f32x4){0.f, 0.f, 0.f, 0.f};

    // staging: 16 chunks of 1024B (8 A + 8 B); wave w owns chunks 2w, 2w+1 of each.
    // chunk c covers rows 16c..16c+15; lane l -> row 16c + (l>>2), LDS colgrp l&3,
    // global colgrp (l&3) ^ (row&3)  [XOR swizzle]
    const int rc = lane >> 2;                    // row within chunk
    const int cg = (lane & 3) ^ (rc & 3);        // swizzled global col group
    const int c0 = 2 * w, c1 = 2 * w + 1;
    const bf16_t* ag0 = A  + (size_t)(m0 + 16 * c0 + rc) * K + cg * 8;
    const bf16_t* ag1 = A  + (size_t)(m0 + 16 * c1 + rc) * K + cg * 8;
    const bf16_t* bg0 = Bm + (size_t)(n0 + 16 * c0 + rc) * K + cg * 8;
    const bf16_t* bg1 = Bm + (size_t)(n0 + 16 * c1 + rc) * K + cg * 8;
    bf16_t* al0 = &As[c0 * 512];
    bf16_t* al1 = &As[c1 * 512];
    bf16_t* bl0 = &Bs[c0 * 512];
    bf16_t* bl1 = &Bs[c1 * 512];

    const int swz8 = (quad ^ (qcol & 3)) * 8;    // fragment-read swizzle

    for (int k0 = 0; k0 < K; k0 += 32) {
        __syncthreads();
        __builtin_amdgcn_global_load_lds(GLB(ag0 + k0), LDS(al0), 16, 0, 0);
        __builtin_amdgcn_global_load_lds(GLB(ag1 + k0), LDS(al1), 16, 0, 0);
        __builtin_amdgcn_global_load_lds(GLB(bg0 + k0), LDS(bl0), 16, 0, 0);
        __builtin_amdgcn_global_load_lds(GLB(bg1 + k0), LDS(bl1), 16, 0, 0);
        __syncthreads();

        bf16x8 af[4], bf[4];
#pragma unroll
        for (int mt = 0; mt < 4; ++mt)
            af[mt] = *(const bf16x8*)&As[(wm + mt * 16 + qcol) * 32 + swz8];
#pragma unroll
        for (int nt = 0; nt < 4; ++nt)
            bf[nt] = *(const bf16x8*)&Bs[(wn + nt * 16 + qcol) * 32 + swz8];
#pragma unroll
        for (int mt = 0; mt < 4; ++mt)
#pragma unroll
            for (int nt = 0; nt < 4; ++nt)
                acc[mt][nt] = __builtin_amdgcn_mfma_f32_16x16x32_bf16(af[mt], bf[nt], acc[mt][nt], 0, 0, 0);
    }

    // epilogue: C/D layout col = lane&15, row = (lane>>4)*4 + r
#pragma unroll
    for (int mt = 0; mt < 4; ++mt) {
#pragma unroll
        for (int nt = 0; nt < 4; ++nt) {
#pragma unroll
            for (int r = 0; r < 4; ++r) {
                const int m = m0 + wm + mt * 16 + quad * 4 + r;
                const int f = n0 + wn + nt * 16 + qcol;
                const float val = acc[mt][nt][r];
                if (MODE == 0) {
                    const int b     = m >> 9;          // T = 512
                    const int t     = m & 511;
                    const int which = f >> 11;
                    const int h     = (f >> 7) & 15;
                    const int d     = f & 127;
                    if (which == 2) {
                        // v stored transposed: (B, H, hd, T)
                        o2[((size_t)(((b << 4) + h) * 128 + d) << 9) + t] = (bf16_t)val;
                    } else {
                        bf16_t* dst = (which == 0) ? o0 : o1;
                        dst[(size_t)(((b << 4) + h) * 512 + t) * 128 + d] = (bf16_t)val;
                    }
                } else {
                    of[(size_t)m * 2048 + f] = val;
                }
            }
        }
    }
}

// ---------------------------------------------------------------------------
// RoPE (in-place on bf16 q and k; v untouched)
// ---------------------------------------------------------------------------
__global__ void rope_kernel(bf16_t* __restrict__ q, bf16_t* __restrict__ k)
{
    const int id  = blockIdx.x * 256 + threadIdx.x;
    const int arr = id >> 19;
    const int rem = id & ((1 << 19) - 1);
    const int bh  = rem >> 12;
    const int t   = (rem >> 3) & 511;
    const int d   = rem & 7;

    bf16_t* p = (arr ? k : q) + (size_t)(bh * 512 + t) * 128;
    const float x1 = (float)p[d];
    const float x2 = (float)p[d + 8];
    const float freq = __expf(-(float)d * 1.1512925464970229f);  // ln(10000)/8
    const float ang  = (float)t * freq;
    const float c = cosf(ang), s = sinf(ang);
    p[d]     = (bf16_t)(x1 * c - x2 * s);
    p[d + 8] = (bf16_t)(x2 * c + x1 * s);
}

// ---------------------------------------------------------------------------
// MFMA flash attention (verified R3). Block = 256 thr (4 waves) per
// (b, h, 64-query tile). S^T = K·Q^T; shfl softmax; P via LDS; O += P·V.
// ---------------------------------------------------------------------------
#define KLD 136
#define VLD 72
#define PLD 72

__global__ __launch_bounds__(256)
void flash_attn(const bf16_t* __restrict__ q, const bf16_t* __restrict__ k,
                const bf16_t* __restrict__ vT, bf16_t* __restrict__ y)
{
    const int qt = blockIdx.x;
    const int h  = blockIdx.y;
    const int b  = blockIdx.z;
    const int tid  = threadIdx.x;
    const int lane = tid & 63;
    const int w    = tid >> 6;
    const int quad = lane >> 4;
    const int qcol = lane & 15;

    __shared__ __align__(16) bf16_t Ks[64 * KLD];
    __shared__ __align__(16) bf16_t VTs[128 * VLD];
    __shared__ __align__(16) bf16_t Ps[64 * PLD];
    __shared__ __align__(16) float aS[4][16];
    __shared__ __align__(16) float lS[4][16];

    const bf16_t* qb  = q  + (size_t)((b * 16 + h) * 512) * 128;
    const bf16_t* kb  = k  + (size_t)((b * 16 + h) * 512) * 128;
    const bf16_t* vtb = vT + (size_t)((b * 16 + h) * 128) * 512;

    bf16x8 qfrag[4];
    const int qrow = qt * 64 + w * 16 + qcol;
#pragma unroll
    for (int kc = 0; kc < 4; ++kc)
        qfrag[kc] = *(const bf16x8*)&qb[(size_t)qrow * 128 + kc * 32 + quad * 8];

    f32x4 acc_o[8];
#pragma unroll
    for (int nt = 0; nt < 8; ++nt) acc_o[nt] = (f32x4){0.f, 0.f, 0.f, 0.f};
    float m_run = -INFINITY, l_run = 0.f;
    const float scale = 0.08838834764831845f;   // 1/sqrt(128)

    for (int kt = 0; kt <= qt; ++kt) {
        __syncthreads();
#pragma unroll
        for (int p = 0; p < 4; ++p) {
            const int r = p * 16 + (tid >> 4), c = (tid & 15) * 8;
            *(uint4*)&Ks[r * KLD + c] = *(const uint4*)&kb[(size_t)(kt * 64 + r) * 128 + c];
        }
#pragma unroll
        for (int p = 0; p < 4; ++p) {
            const int r = p * 32 + (tid >> 3), c = (tid & 7) * 8;
            *(uint4*)&VTs[r * VLD + c] = *(const uint4*)&vtb[(size_t)r * 512 + kt * 64 + c];
        }
        __syncthreads();

        f32x4 sacc[4];
#pragma unroll
        for (int mt = 0; mt < 4; ++mt) sacc[mt] = (f32x4){0.f, 0.f, 0.f, 0.f};
#pragma unroll
        for (int mt = 0; mt < 4; ++mt)
#pragma unroll
            for (int kc = 0; kc < 4; ++kc) {
                bf16x8 af = *(const bf16x8*)&Ks[(mt * 16 + qcol) * KLD + kc * 32 + quad * 8];
                sacc[mt] = __builtin_amdgcn_mfma_f32_16x16x32_bf16(af, qfrag[kc], sacc[mt], 0, 0, 0);
            }

        float s[16];
#pragma unroll
        for (int mt = 0; mt < 4; ++mt)
#pragma unroll
            for (int r = 0; r < 4; ++r)
                s[mt * 4 + r] = sacc[mt][r] * scale;
        if (kt == qt) {
#pragma unroll
            for (int mt = 0; mt < 4; ++mt)
#pragma unroll
                for (int r = 0; r < 4; ++r)
                    if (mt * 16 + quad * 4 + r > w * 16 + qcol)
                        s[mt * 4 + r] = -1e30f;
        }

        float mx = s[0];
#pragma unroll
        for (int i = 1; i < 16; ++i) mx = fmaxf(mx, s[i]);
        mx = fmaxf(mx, __shfl_xor(mx, 16));
        mx = fmaxf(mx, __shfl_xor(mx, 32));
        const float m_new = fmaxf(m_run, mx);
        const float alpha = __expf(m_run - m_new);
        float p16[16];
        float sum = 0.f;
#pragma unroll
        for (int i = 0; i < 16; ++i) { p16[i] = __expf(s[i] - m_new); sum += p16[i]; }
        sum += __shfl_xor(sum, 16);
        sum += __shfl_xor(sum, 32);
        l_run = l_run * alpha + sum;
        m_run = m_new;
        if (quad == 0) aS[w][qcol] = alpha;

#pragma unroll
        for (int mt = 0; mt < 4; ++mt) {
            bf16x4 pb = {(bf16_t)p16[mt * 4 + 0], (bf16_t)p16[mt * 4 + 1],
                         (bf16_t)p16[mt * 4 + 2], (bf16_t)p16[mt * 4 + 3]};
            *(bf16x4*)&Ps[(w * 16 + qcol) * PLD + mt * 16 + quad * 4] = pb;
        }

        f32x4 alpha4 = *(const f32x4*)&aS[w][quad * 4];
#pragma unroll
        for (int nt = 0; nt < 8; ++nt)
#pragma unroll
            for (int r = 0; r < 4; ++r)
                acc_o[nt][r] *= alpha4[r];

#pragma unroll
        for (int kc2 = 0; kc2 < 2; ++kc2) {
            bf16x8 pf = *(const bf16x8*)&Ps[(w * 16 + qcol) * PLD + kc2 * 32 + quad * 8];
#pragma unroll
            for (int nt = 0; nt < 8; ++nt) {
                bf16x8 vf = *(const bf16x8*)&VTs[(nt * 16 + qcol) * VLD + kc2 * 32 + quad * 8];
                acc_o[nt] = __builtin_amdgcn_mfma_f32_16x16x32_bf16(pf, vf, acc_o[nt], 0, 0, 0);
            }
        }
    }

    if (quad == 0) lS[w][qcol] = l_run;
    f32x4 l4 = *(const f32x4*)&lS[w][quad * 4];
#pragma unroll
    for (int nt = 0; nt < 8; ++nt)
#pragma unroll
        for (int r = 0; r < 4; ++r) {
            const int t  = qt * 64 + w * 16 + quad * 4 + r;
            const int cc = h * 128 + nt * 16 + qcol;
            y[(size_t)(b * 512 + t) * 2048 + cc] = (bf16_t)(acc_o[nt][r] / l4[r]);
        }
}

// ---------------------------------------------------------------------------
extern "C" void kernel_launch(void* const* d_in, const int* in_sizes, int n_in,
                              void* d_out, int out_size, void* d_ws, size_t ws_size,
                              hipStream_t stream)
{
    (void)in_sizes; (void)n_in; (void)out_size; (void)ws_size;

    const float* x    = (const float*)d_in[0];   // (8, 512, 2048) fp32
    const float* Wqkv = (const float*)d_in[1];   // (6144, 2048)  fp32
    const float* Wout = (const float*)d_in[2];   // (2048, 2048)  fp32
    float* out = (float*)d_out;                  // (8, 512, 2048) fp32

    const size_t SEG = (size_t)8 * 16 * 512 * 128;   // 8,388,608 elems (16 MB bf16)
    bf16_t* q      = (bf16_t*)d_ws;          // [0, 16 MB)
    bf16_t* k      = q + SEG;                // [16, 32)
    bf16_t* vT     = k + SEG;                // [32, 48)   (B,H,hd,T)
    bf16_t* xb     = vT + SEG;               // [48, 64)   bf16 x — dead after GEMM1
    bf16_t* y      = xb;                     //            y aliases xb (born in flash)
    bf16_t* Wqkvb  = xb + SEG;               // [64, 88)   bf16 Wqkv
    bf16_t* Woutb  = Wqkvb + (size_t)6144 * 2048;   // [88, 96)
    // total ws use: 96 MB

    // 0) fp32 -> bf16 converts
    f32_to_bf16<<<(8388608 / 8) / 256, 256, 0, stream>>>(x, xb, 8388608 / 8);
    f32_to_bf16<<<(12582912 / 8) / 256, 256, 0, stream>>>(Wqkv, Wqkvb, 12582912 / 8);
    f32_to_bf16<<<(4194304 / 8) / 256, 256, 0, stream>>>(Wout, Woutb, 4194304 / 8);
    // 1) qkv = x @ Wqkv^T -> q, k (B,H,T,hd), vT (B,H,hd,T)
    gemm_bt<0><<<dim3(4096 / 128, 6144 / 128), 256, 0, stream>>>(xb, Wqkvb, 2048, q, k, vT, nullptr);
    // 2) RoPE in-place
    rope_kernel<<<(2 * 128 * 512 * 8) / 256, 256, 0, stream>>>(q, k);
    // 3) flash attention -> y (aliases xb; GEMM1 is done with xb by now)
    flash_attn<<<dim3(8, 16, 8), 256, 0, stream>>>(q, k, vT, y);
    // 4) out = y @ Wout^T (fp32 store)
    gemm_bt<1><<<dim3(4096 / 128, 2048 / 128), 256, 0, stream>>>(y, Woutb, 2048, nullptr, nullptr, nullptr, out);
}

// Round 5
// 375.570 us; speedup vs baseline: 2.9067x; 1.0419x over previous
//
#include <hip/hip_runtime.h>

typedef __bf16 bf16_t;
typedef __bf16 bf16x4 __attribute__((ext_vector_type(4)));
typedef __bf16 bf16x8 __attribute__((ext_vector_type(8)));
typedef float f32x4 __attribute__((ext_vector_type(4)));

#define GLB(p) ((const __attribute__((address_space(1))) void*)(p))
#define LDS(p) ((__attribute__((address_space(3))) void*)(p))

// ---------------------------------------------------------------------------
// fp32 -> bf16 bulk convert (8 elems/thread, 16B stores)
// ---------------------------------------------------------------------------
__global__ void f32_to_bf16(const float* __restrict__ src, bf16_t* __restrict__ dst, int n8)
{
    const int i = blockIdx.x * 256 + threadIdx.x;
    if (i >= n8) return;
    const f32x4 a = *(const f32x4*)&src[(size_t)i * 8];
    const f32x4 b = *(const f32x4*)&src[(size_t)i * 8 + 4];
    bf16x8 h = {(bf16_t)a[0], (bf16_t)a[1], (bf16_t)a[2], (bf16_t)a[3],
                (bf16_t)b[0], (bf16_t)b[1], (bf16_t)b[2], (bf16_t)b[3]};
    *(bf16x8*)&dst[(size_t)i * 8] = h;
}

// ---------------------------------------------------------------------------
// m97-structure GEMM (R4-verified, 656 TF): 128x128 tile, BK=32, 4 waves.
// global_load_lds width=16 into unpadded LDS with XOR column swizzle.
// MODE 0: scatter -> q/k (B,H,T,hd), vT (B,H,hd,T).  MODE 1: fp32 store.
// ---------------------------------------------------------------------------
template <int MODE>
__global__ __launch_bounds__(256)
void gemm_bt(const bf16_t* __restrict__ A, const bf16_t* __restrict__ Bm, int K,
             bf16_t* __restrict__ o0, bf16_t* __restrict__ o1, bf16_t* __restrict__ o2,
             float* __restrict__ of)
{
    __shared__ __align__(16) bf16_t As[128 * 32];
    __shared__ __align__(16) bf16_t Bs[128 * 32];
    const int tid  = threadIdx.x;
    const int lane = tid & 63;
    const int w    = tid >> 6;
    const int wm   = (w & 1) * 64;
    const int wn   = (w >> 1) * 64;
    const int m0   = blockIdx.x * 128;
    const int n0   = blockIdx.y * 128;
    const int quad = lane >> 4;
    const int qcol = lane & 15;

    f32x4 acc[4][4];
#pragma unroll
    for (int i = 0; i < 4; ++i)
#pragma unroll
        for (int j = 0; j < 4; ++j)
            acc[i][j] = (f32x4){0.f, 0.f, 0.f, 0.f};

    const int rc = lane >> 2;
    const int cg = (lane & 3) ^ (rc & 3);        // XOR-swizzled global col group
    const int c0 = 2 * w, c1 = 2 * w + 1;
    const bf16_t* ag0 = A  + (size_t)(m0 + 16 * c0 + rc) * K + cg * 8;
    const bf16_t* ag1 = A  + (size_t)(m0 + 16 * c1 + rc) * K + cg * 8;
    const bf16_t* bg0 = Bm + (size_t)(n0 + 16 * c0 + rc) * K + cg * 8;
    const bf16_t* bg1 = Bm + (size_t)(n0 + 16 * c1 + rc) * K + cg * 8;
    bf16_t* al0 = &As[c0 * 512];
    bf16_t* al1 = &As[c1 * 512];
    bf16_t* bl0 = &Bs[c0 * 512];
    bf16_t* bl1 = &Bs[c1 * 512];

    const int swz8 = (quad ^ (qcol & 3)) * 8;

    for (int k0 = 0; k0 < K; k0 += 32) {
        __syncthreads();
        __builtin_amdgcn_global_load_lds(GLB(ag0 + k0), LDS(al0), 16, 0, 0);
        __builtin_amdgcn_global_load_lds(GLB(ag1 + k0), LDS(al1), 16, 0, 0);
        __builtin_amdgcn_global_load_lds(GLB(bg0 + k0), LDS(bl0), 16, 0, 0);
        __builtin_amdgcn_global_load_lds(GLB(bg1 + k0), LDS(bl1), 16, 0, 0);
        __syncthreads();

        bf16x8 af[4], bf[4];
#pragma unroll
        for (int mt = 0; mt < 4; ++mt)
            af[mt] = *(const bf16x8*)&As[(wm + mt * 16 + qcol) * 32 + swz8];
#pragma unroll
        for (int nt = 0; nt < 4; ++nt)
            bf[nt] = *(const bf16x8*)&Bs[(wn + nt * 16 + qcol) * 32 + swz8];
#pragma unroll
        for (int mt = 0; mt < 4; ++mt)
#pragma unroll
            for (int nt = 0; nt < 4; ++nt)
                acc[mt][nt] = __builtin_amdgcn_mfma_f32_16x16x32_bf16(af[mt], bf[nt], acc[mt][nt], 0, 0, 0);
    }

#pragma unroll
    for (int mt = 0; mt < 4; ++mt) {
#pragma unroll
        for (int nt = 0; nt < 4; ++nt) {
#pragma unroll
            for (int r = 0; r < 4; ++r) {
                const int m = m0 + wm + mt * 16 + quad * 4 + r;
                const int f = n0 + wn + nt * 16 + qcol;
                const float val = acc[mt][nt][r];
                if (MODE == 0) {
                    const int b     = m >> 9;          // T = 512
                    const int t     = m & 511;
                    const int which = f >> 11;
                    const int h     = (f >> 7) & 15;
                    const int d     = f & 127;
                    if (which == 2) {
                        o2[((size_t)(((b << 4) + h) * 128 + d) << 9) + t] = (bf16_t)val;
                    } else {
                        bf16_t* dst = (which == 0) ? o0 : o1;
                        dst[(size_t)(((b << 4) + h) * 512 + t) * 128 + d] = (bf16_t)val;
                    }
                } else {
                    of[(size_t)m * 2048 + f] = val;
                }
            }
        }
    }
}

// ---------------------------------------------------------------------------
// RoPE (in-place on bf16 q and k; v untouched)
// ---------------------------------------------------------------------------
__global__ void rope_kernel(bf16_t* __restrict__ q, bf16_t* __restrict__ k)
{
    const int id  = blockIdx.x * 256 + threadIdx.x;
    const int arr = id >> 19;
    const int rem = id & ((1 << 19) - 1);
    const int bh  = rem >> 12;
    const int t   = (rem >> 3) & 511;
    const int d   = rem & 7;

    bf16_t* p = (arr ? k : q) + (size_t)(bh * 512 + t) * 128;
    const float x1 = (float)p[d];
    const float x2 = (float)p[d + 8];
    const float freq = __expf(-(float)d * 1.1512925464970229f);  // ln(10000)/8
    const float ang  = (float)t * freq;
    const float c = cosf(ang), s = sinf(ang);
    p[d]     = (bf16_t)(x1 * c - x2 * s);
    p[d + 8] = (bf16_t)(x2 * c + x1 * s);
}

// ---------------------------------------------------------------------------
// MFMA flash attention, BQ=128, BK=64. Block = 256 thr (4 waves) per
// (b, h, 128-query tile). Wave w owns 32 queries (2 x 16-query groups qg).
// S^T = K·Q^T (query = lane&15 per qg); shfl softmax; P via wave-private LDS;
// O += P·V with V^T staged from (B,H,hd,T) global.
// ---------------------------------------------------------------------------
#define KLD 136
#define VLD 72
#define PLD 72

__global__ __launch_bounds__(256)
void flash_attn(const bf16_t* __restrict__ q, const bf16_t* __restrict__ k,
                const bf16_t* __restrict__ vT, bf16_t* __restrict__ y)
{
    const int qtb = blockIdx.x;   // 0..3 (128-query tiles)
    const int h   = blockIdx.y;
    const int b   = blockIdx.z;
    const int tid  = threadIdx.x;
    const int lane = tid & 63;
    const int w    = tid >> 6;
    const int quad = lane >> 4;
    const int qcol = lane & 15;

    __shared__ __align__(16) bf16_t Ks[64 * KLD];      // keys x dims
    __shared__ __align__(16) bf16_t VTs[128 * VLD];    // dims x keys
    __shared__ __align__(16) bf16_t Ps[128 * PLD];     // queries x keys
    __shared__ __align__(16) float aS[4][2][16];
    __shared__ __align__(16) float lS[4][2][16];

    const bf16_t* qb  = q  + (size_t)((b * 16 + h) * 512) * 128;
    const bf16_t* kb  = k  + (size_t)((b * 16 + h) * 512) * 128;
    const bf16_t* vtb = vT + (size_t)((b * 16 + h) * 128) * 512;

    // Q fragments (B-operand): query = qtb*128 + w*32 + qg*16 + qcol
    bf16x8 qfrag[2][4];
#pragma unroll
    for (int qg = 0; qg < 2; ++qg) {
        const int qrow = qtb * 128 + w * 32 + qg * 16 + qcol;
#pragma unroll
        for (int kc = 0; kc < 4; ++kc)
            qfrag[qg][kc] = *(const bf16x8*)&qb[(size_t)qrow * 128 + kc * 32 + quad * 8];
    }

    f32x4 acc_o[2][8];
#pragma unroll
    for (int qg = 0; qg < 2; ++qg)
#pragma unroll
        for (int nt = 0; nt < 8; ++nt) acc_o[qg][nt] = (f32x4){0.f, 0.f, 0.f, 0.f};
    float m_run[2] = {-INFINITY, -INFINITY};
    float l_run[2] = {0.f, 0.f};
    const float scale = 0.08838834764831845f;   // 1/sqrt(128)

    const int kt_last = 2 * qtb + 1;
    for (int kt = 0; kt <= kt_last; ++kt) {
        __syncthreads();
        // stage K tile (64 keys x 128 dims)
#pragma unroll
        for (int p = 0; p < 4; ++p) {
            const int r = p * 16 + (tid >> 4), c = (tid & 15) * 8;
            *(uint4*)&Ks[r * KLD + c] = *(const uint4*)&kb[(size_t)(kt * 64 + r) * 128 + c];
        }
        // stage V^T tile (128 dims x 64 keys)
#pragma unroll
        for (int p = 0; p < 4; ++p) {
            const int r = p * 32 + (tid >> 3), c = (tid & 7) * 8;
            *(uint4*)&VTs[r * VLD + c] = *(const uint4*)&vtb[(size_t)r * 512 + kt * 64 + c];
        }
        __syncthreads();

        const bool need_mask = (kt >= 2 * qtb);

#pragma unroll
        for (int qg = 0; qg < 2; ++qg) {
            // S^T (M=64 keys, N=16 queries, K=128): 16 MFMA
            f32x4 sacc[4];
#pragma unroll
            for (int mt = 0; mt < 4; ++mt) sacc[mt] = (f32x4){0.f, 0.f, 0.f, 0.f};
#pragma unroll
            for (int mt = 0; mt < 4; ++mt)
#pragma unroll
                for (int kc = 0; kc < 4; ++kc) {
                    bf16x8 af = *(const bf16x8*)&Ks[(mt * 16 + qcol) * KLD + kc * 32 + quad * 8];
                    sacc[mt] = __builtin_amdgcn_mfma_f32_16x16x32_bf16(af, qfrag[qg][kc], sacc[mt], 0, 0, 0);
                }

            float s[16];
#pragma unroll
            for (int mt = 0; mt < 4; ++mt)
#pragma unroll
                for (int r = 0; r < 4; ++r)
                    s[mt * 4 + r] = sacc[mt][r] * scale;
            if (need_mask) {
                const int qglob = qtb * 128 + w * 32 + qg * 16 + qcol;
#pragma unroll
                for (int mt = 0; mt < 4; ++mt)
#pragma unroll
                    for (int r = 0; r < 4; ++r)
                        if (kt * 64 + mt * 16 + quad * 4 + r > qglob)
                            s[mt * 4 + r] = -1e30f;
            }

            float mx = s[0];
#pragma unroll
            for (int i = 1; i < 16; ++i) mx = fmaxf(mx, s[i]);
            mx = fmaxf(mx, __shfl_xor(mx, 16));
            mx = fmaxf(mx, __shfl_xor(mx, 32));
            const float m_new = fmaxf(m_run[qg], mx);
            const float alpha = __expf(m_run[qg] - m_new);   // first iter: exp(-inf)=0
            float p16[16];
            float sum = 0.f;
#pragma unroll
            for (int i = 0; i < 16; ++i) { p16[i] = __expf(s[i] - m_new); sum += p16[i]; }
            sum += __shfl_xor(sum, 16);
            sum += __shfl_xor(sum, 32);
            l_run[qg] = l_run[qg] * alpha + sum;
            m_run[qg] = m_new;
            if (quad == 0) aS[w][qg][qcol] = alpha;

            // P -> wave-private LDS rows [w*32 + qg*16, +16)
#pragma unroll
            for (int mt = 0; mt < 4; ++mt) {
                bf16x4 pb = {(bf16_t)p16[mt * 4 + 0], (bf16_t)p16[mt * 4 + 1],
                             (bf16_t)p16[mt * 4 + 2], (bf16_t)p16[mt * 4 + 3]};
                *(bf16x4*)&Ps[(w * 32 + qg * 16 + qcol) * PLD + mt * 16 + quad * 4] = pb;
            }

            // rescale O rows (query = quad*4 + r within qg) by alpha
            f32x4 alpha4 = *(const f32x4*)&aS[w][qg][quad * 4];
#pragma unroll
            for (int nt = 0; nt < 8; ++nt)
#pragma unroll
                for (int r = 0; r < 4; ++r)
                    acc_o[qg][nt][r] *= alpha4[r];

            // O += P·V (M=16 queries, N=128 dims, K=64 keys): 16 MFMA
#pragma unroll
            for (int kc2 = 0; kc2 < 2; ++kc2) {
                bf16x8 pf = *(const bf16x8*)&Ps[(w * 32 + qg * 16 + qcol) * PLD + kc2 * 32 + quad * 8];
#pragma unroll
                for (int nt = 0; nt < 8; ++nt) {
                    bf16x8 vf = *(const bf16x8*)&VTs[(nt * 16 + qcol) * VLD + kc2 * 32 + quad * 8];
                    acc_o[qg][nt] = __builtin_amdgcn_mfma_f32_16x16x32_bf16(pf, vf, acc_o[qg][nt], 0, 0, 0);
                }
            }
        }
    }

    // epilogue: y[(b, t, h*128 + d)] = O / l
    if (quad == 0) { lS[w][0][qcol] = l_run[0]; lS[w][1][qcol] = l_run[1]; }
#pragma unroll
    for (int qg = 0; qg < 2; ++qg) {
        f32x4 l4 = *(const f32x4*)&lS[w][qg][quad * 4];
#pragma unroll
        for (int nt = 0; nt < 8; ++nt)
#pragma unroll
            for (int r = 0; r < 4; ++r) {
                const int t  = qtb * 128 + w * 32 + qg * 16 + quad * 4 + r;
                const int cc = h * 128 + nt * 16 + qcol;
                y[(size_t)(b * 512 + t) * 2048 + cc] = (bf16_t)(acc_o[qg][nt][r] / l4[r]);
            }
    }
}

// ---------------------------------------------------------------------------
extern "C" void kernel_launch(void* const* d_in, const int* in_sizes, int n_in,
                              void* d_out, int out_size, void* d_ws, size_t ws_size,
                              hipStream_t stream)
{
    (void)in_sizes; (void)n_in; (void)out_size; (void)ws_size;

    const float* x    = (const float*)d_in[0];   // (8, 512, 2048) fp32
    const float* Wqkv = (const float*)d_in[1];   // (6144, 2048)  fp32
    const float* Wout = (const float*)d_in[2];   // (2048, 2048)  fp32
    float* out = (float*)d_out;                  // (8, 512, 2048) fp32

    const size_t SEG = (size_t)8 * 16 * 512 * 128;   // 8,388,608 elems (16 MB bf16)
    bf16_t* q      = (bf16_t*)d_ws;          // [0, 16 MB)
    bf16_t* k      = q + SEG;                // [16, 32)
    bf16_t* vT     = k + SEG;                // [32, 48)   (B,H,hd,T)
    bf16_t* xb     = vT + SEG;               // [48, 64)   bf16 x — dead after GEMM1
    bf16_t* y      = xb;                     //            y aliases xb
    bf16_t* Wqkvb  = xb + SEG;               // [64, 88)   bf16 Wqkv
    bf16_t* Woutb  = Wqkvb + (size_t)6144 * 2048;   // [88, 96)

    f32_to_bf16<<<(8388608 / 8) / 256, 256, 0, stream>>>(x, xb, 8388608 / 8);
    f32_to_bf16<<<(12582912 / 8) / 256, 256, 0, stream>>>(Wqkv, Wqkvb, 12582912 / 8);
    f32_to_bf16<<<(4194304 / 8) / 256, 256, 0, stream>>>(Wout, Woutb, 4194304 / 8);
    gemm_bt<0><<<dim3(4096 / 128, 6144 / 128), 256, 0, stream>>>(xb, Wqkvb, 2048, q, k, vT, nullptr);
    rope_kernel<<<(2 * 128 * 512 * 8) / 256, 256, 0, stream>>>(q, k);
    flash_attn<<<dim3(4, 16, 8), 256, 0, stream>>>(q, k, vT, y);
    gemm_bt<1><<<dim3(4096 / 128, 2048 / 128), 256, 0, stream>>>(y, Woutb, 2048, nullptr, nullptr, nullptr, out);
}